// Round 7
// baseline (466.730 us; speedup 1.0000x reference)
//
#include <hip/hip_runtime.h>
#include <hip/hip_bf16.h>
#include <stdint.h>

#define Bdim 4
#define Hdim 8
#define Ndim 2048
#define Cdim 512
#define Ddim 64
#define SCALE_F 0.125f
#define KSPLIT 4
#define LOG2E 1.44269504f
// Q pre-scale folds softmax scale AND log2(e) so attn uses exp2(s) directly.
#define QSCALE_F (SCALE_F * LOG2E)

typedef __bf16 bf16_t;
typedef __bf16 bf16x8 __attribute__((ext_vector_type(8)));
typedef float f32x4 __attribute__((ext_vector_type(4)));

// ---------------------------------------------------------------------------
// Gumbel factors: JAX threefry2x32, key (0,42), partitionable path:
// counter words (hi=0, lo=flat), bits32 = out0 ^ out1.  Round-major SoA
// (16 streams advance together).  u = bitcast(bits>>9 | 0x3f800000) - 1
// (tiny dropped: only matters for bits>>9==0, ~16 of 134M elems -> <1e-4).
// Softmax identity: exp(s+g) = exp(s)/(-ln u); global ln2 cancels in o/l.
// pf = -rcp(log2(u)).  Mantissa insert via single v_alignbit_b32.
// Stream i = r*4+j has counter base + (r<<11) + j*16 (+42 prefolded).
// ---------------------------------------------------------------------------
__device__ __forceinline__ void gumbel_tile(uint32_t base, float (&pf)[4][4]) {
  const uint32_t k1 = 42u, k2 = 0x1BD11BDAu ^ 42u;
  uint32_t s0[16], s1[16];
#pragma unroll
  for (int i = 0; i < 16; i++) {
    s0[i] = 0u;
    s1[i] = base + ((uint32_t)(i >> 2) << 11) + (uint32_t)((i & 3) * 16);
  }
#define TF_RND(rot)                                                    \
  {                                                                    \
    _Pragma("unroll") for (int i = 0; i < 16; i++) {                   \
      s0[i] += s1[i];                                                  \
      s1[i] = __builtin_rotateleft32(s1[i], (rot)) ^ s0[i];            \
    }                                                                  \
  }
#define TF_INJ(a, b)                                                   \
  {                                                                    \
    _Pragma("unroll") for (int i = 0; i < 16; i++) {                   \
      s0[i] += (a);                                                    \
      s1[i] += (b);                                                    \
    }                                                                  \
  }
#define TF_INJ1(b)                                                     \
  {                                                                    \
    _Pragma("unroll") for (int i = 0; i < 16; i++) { s1[i] += (b); }   \
  }
  TF_RND(13) TF_RND(15) TF_RND(26) TF_RND(6)
  TF_INJ(k1, k2 + 1u)
  TF_RND(17) TF_RND(29) TF_RND(16) TF_RND(24)
  TF_INJ(k2, 2u)
  TF_RND(13) TF_RND(15) TF_RND(26) TF_RND(6)
  TF_INJ1(k1 + 3u)                       // x0 += k0 == 0
  TF_RND(17) TF_RND(29) TF_RND(16) TF_RND(24)
  TF_INJ(k1, k2 + 4u)
  TF_RND(13) TF_RND(15) TF_RND(26) TF_RND(6)
  TF_INJ(k2, 5u)
#undef TF_RND
#undef TF_INJ
#undef TF_INJ1
#pragma unroll
  for (int i = 0; i < 16; i++) {
    uint32_t bits = s0[i] ^ s1[i];       // partitionable 32-bit fold
    uint32_t mant;                       // (0x7F<<23) | (bits>>9) in one op
    asm("v_alignbit_b32 %0, %1, %2, 9" : "=v"(mant) : "s"(127u), "v"(bits));
    float u = __uint_as_float(mant) - 1.0f;
    pf[i >> 2][i & 3] = -__builtin_amdgcn_rcpf(__builtin_amdgcn_logf(u));
  }
}

// ---------------------------------------------------------------------------
// fp32 -> bf16x8 staging helper (RNE casts + single b128 LDS write)
// ---------------------------------------------------------------------------
__device__ __forceinline__ void stage8_f32(bf16_t* dst, const float* src) {
  float4 a0 = *(const float4*)src;
  float4 a1 = *(const float4*)(src + 4);
  union { bf16_t h[8]; uint4 u; } pk;
  pk.h[0] = (bf16_t)a0.x; pk.h[1] = (bf16_t)a0.y;
  pk.h[2] = (bf16_t)a0.z; pk.h[3] = (bf16_t)a0.w;
  pk.h[4] = (bf16_t)a1.x; pk.h[5] = (bf16_t)a1.y;
  pk.h[6] = (bf16_t)a1.z; pk.h[7] = (bf16_t)a1.w;
  *(uint4*)dst = pk.u;
}

// ---------------------------------------------------------------------------
// NT GEMM core: C[m][n] = sum_k A[m0+m][k] * W[n0+n][k], K = 512.
// Block 256 thr = 4 waves (2x2), each wave 64x64. Tiles 128x128, BK = 64.
// mfma_f32_16x16x32_bf16: A/B frag [row=lane&15][k=quad*8+j], C/D row=quad*4+r.
// fp32 sources converted to bf16 during staging (no separate cvt kernels).
// ---------------------------------------------------------------------------
template <bool AF32, bool WF32>
__device__ __forceinline__ void gemm_core_t(const void* __restrict__ Av,
                                            const void* __restrict__ Wv,
                                            int m0, int n0,
                                            bf16_t* As, bf16_t* Ws,
                                            f32x4 (&acc)[4][4]) {
  const int t = threadIdx.x;
  const int wave = t >> 6, lane = t & 63;
  const int ln = lane & 15, qd = lane >> 4;
  const int wm = wave >> 1, wn = wave & 1;

#pragma unroll
  for (int i = 0; i < 4; i++)
#pragma unroll
    for (int j = 0; j < 4; j++) acc[i][j] = (f32x4){0.f, 0.f, 0.f, 0.f};

  for (int kt = 0; kt < Cdim / 64; ++kt) {
#pragma unroll
    for (int it = 0; it < 4; ++it) {
      int vec = it * 256 + t;
      int row = vec >> 3, c8 = (vec & 7) * 8;
      if constexpr (AF32)
        stage8_f32(&As[row * 72 + c8],
                   (const float*)Av + (size_t)(m0 + row) * Cdim + kt * 64 + c8);
      else
        *(bf16x8*)&As[row * 72 + c8] =
            *((const bf16x8*)Av + ((size_t)(m0 + row) * Cdim + kt * 64 + c8) / 8);
      if constexpr (WF32)
        stage8_f32(&Ws[row * 72 + c8],
                   (const float*)Wv + (size_t)(n0 + row) * Cdim + kt * 64 + c8);
      else
        *(bf16x8*)&Ws[row * 72 + c8] =
            *((const bf16x8*)Wv + ((size_t)(n0 + row) * Cdim + kt * 64 + c8) / 8);
    }
    __syncthreads();
#pragma unroll
    for (int ks = 0; ks < 2; ++ks) {
      bf16x8 af[4], bfr[4];
#pragma unroll
      for (int i = 0; i < 4; i++)
        af[i] = *(const bf16x8*)&As[(wm * 64 + i * 16 + ln) * 72 + ks * 32 + qd * 8];
#pragma unroll
      for (int j = 0; j < 4; j++)
        bfr[j] = *(const bf16x8*)&Ws[(wn * 64 + j * 16 + ln) * 72 + ks * 32 + qd * 8];
#pragma unroll
      for (int i = 0; i < 4; i++)
#pragma unroll
        for (int j = 0; j < 4; j++)
          acc[i][j] = __builtin_amdgcn_mfma_f32_16x16x32_bf16(af[i], bfr[j],
                                                              acc[i][j], 0, 0, 0);
    }
    __syncthreads();
  }
}

// QKV projections fused over blockIdx.z; epilogue scatters to [B,H,L,D] bf16.
// Q (sel==0) is pre-scaled by SCALE*LOG2E so attn uses exp2(s) with no mul.
__global__ __launch_bounds__(256, 3)
void qkv_gemm_kernel(const float* __restrict__ x, const float* __restrict__ y,
                     const float* __restrict__ z, const float* __restrict__ Wq,
                     const float* __restrict__ Wk, const float* __restrict__ Wv,
                     const float* __restrict__ bq, const float* __restrict__ bk,
                     const float* __restrict__ bv, bf16_t* __restrict__ qo,
                     bf16_t* __restrict__ ko, bf16_t* __restrict__ vo) {
  __shared__ bf16_t As[128 * 72];
  __shared__ bf16_t Ws[128 * 72];
  const int sel = blockIdx.z;
  const float* A = sel == 0 ? x : (sel == 1 ? y : z);
  const float* W = sel == 0 ? Wq : (sel == 1 ? Wk : Wv);
  const float* bias = sel == 0 ? bq : (sel == 1 ? bk : bv);
  bf16_t* O = sel == 0 ? qo : (sel == 1 ? ko : vo);
  const float mul = sel == 0 ? QSCALE_F : 1.0f;
  const int m0 = blockIdx.y * 128, n0 = blockIdx.x * 128;

  f32x4 acc[4][4];
  gemm_core_t<true, true>(A, W, m0, n0, As, Ws, acc);

  const int t = threadIdx.x;
  const int wave = t >> 6, lane = t & 63;
  const int ln = lane & 15, qd = lane >> 4;
  const int wm = wave >> 1, wn = wave & 1;
#pragma unroll
  for (int i = 0; i < 4; i++)
#pragma unroll
    for (int j = 0; j < 4; j++)
#pragma unroll
      for (int r = 0; r < 4; r++) {
        int grow = m0 + wm * 64 + i * 16 + qd * 4 + r;
        int gcol = n0 + wn * 64 + j * 16 + ln;
        float val = (acc[i][j][r] + bias[gcol]) * mul;
        int b = grow >> 11, n = grow & 2047;
        int h = gcol >> 6, d = gcol & 63;
        O[(((size_t)b * Hdim + h) * Ndim + n) * Ddim + d] = (bf16_t)val;
      }
}

// ---------------------------------------------------------------------------
// Output projection with FUSED COMBINE (R13): A-tile staging gathers the
// KSPLIT partial-O tiles, sums, multiplies by 1/sum(l), converts to bf16 --
// bit-identical to the former combine-kernel-then-GEMM path (same fadd order,
// same 1.0f/l, same RNE).  kt indexes the K-chunk == head h (Cdim = H*D).
// Tile 128(M) x 64(N), 512 blocks, 4 waves (2x2), wave = 64x32, acc[4][2].
// Kills the attn_combine dispatch and the 16 MB ab round-trip.
// ---------------------------------------------------------------------------
__global__ __launch_bounds__(256, 4)
void out_gemm_kernel(const bf16_t* __restrict__ part_o,
                     const float* __restrict__ part_l,
                     const float* __restrict__ Wo,
                     const float* __restrict__ bo, float* __restrict__ out) {
  __shared__ bf16_t As[128 * 72];
  __shared__ bf16_t Ws[64 * 72];
  const int t = threadIdx.x;
  const int wave = t >> 6, lane = t & 63;
  const int ln = lane & 15, qd = lane >> 4;
  const int wm = wave >> 1, wn = wave & 1;
  const int m0 = blockIdx.y * 128, n0 = blockIdx.x * 64;

  f32x4 acc[4][2];
#pragma unroll
  for (int i = 0; i < 4; i++)
#pragma unroll
    for (int j = 0; j < 2; j++) acc[i][j] = (f32x4){0.f, 0.f, 0.f, 0.f};

  for (int kt = 0; kt < Cdim / 64; ++kt) {   // kt == head h
    // stage A = combine(part_o, part_l) for head kt, rows m0..m0+127
#pragma unroll
    for (int it = 0; it < 4; ++it) {
      int vec = it * 256 + t;
      int row = vec >> 3, c8 = (vec & 7) * 8;
      int grow = m0 + row;
      int b = grow >> 11, n = grow & 2047;
      int qtile = n >> 6, r64 = n & 63;
      int blk = (((b * Hdim + kt) << 5) | qtile) * KSPLIT;
      const bf16_t* po = part_o + (size_t)blk * 4096 + r64 * 64 + c8;
      float l = part_l[(size_t)blk * 64 + r64] +
                part_l[(size_t)(blk + 1) * 64 + r64] +
                part_l[(size_t)(blk + 2) * 64 + r64] +
                part_l[(size_t)(blk + 3) * 64 + r64];
      float linv = 1.0f / l;
      float a8[8] = {0.f, 0.f, 0.f, 0.f, 0.f, 0.f, 0.f, 0.f};
#pragma unroll
      for (int zz = 0; zz < KSPLIT; zz++) {
        bf16x8 v = *(const bf16x8*)(po + (size_t)zz * 4096);
#pragma unroll
        for (int i = 0; i < 8; i++) a8[i] += (float)v[i];
      }
      union { bf16_t h[8]; uint4 u; } pk;
#pragma unroll
      for (int i = 0; i < 8; i++) pk.h[i] = (bf16_t)(a8[i] * linv);
      *(uint4*)&As[row * 72 + c8] = pk.u;
    }
    // stage W (fp32 -> bf16)
#pragma unroll
    for (int it = 0; it < 2; ++it) {
      int vec = it * 256 + t;
      int row = vec >> 3, c8 = (vec & 7) * 8;
      stage8_f32(&Ws[row * 72 + c8],
                 Wo + (size_t)(n0 + row) * Cdim + kt * 64 + c8);
    }
    __syncthreads();
#pragma unroll
    for (int ks = 0; ks < 2; ++ks) {
      bf16x8 af[4], bfr[2];
#pragma unroll
      for (int i = 0; i < 4; i++)
        af[i] = *(const bf16x8*)&As[(wm * 64 + i * 16 + ln) * 72 + ks * 32 + qd * 8];
#pragma unroll
      for (int j = 0; j < 2; j++)
        bfr[j] = *(const bf16x8*)&Ws[(wn * 32 + j * 16 + ln) * 72 + ks * 32 + qd * 8];
#pragma unroll
      for (int i = 0; i < 4; i++)
#pragma unroll
        for (int j = 0; j < 2; j++)
          acc[i][j] = __builtin_amdgcn_mfma_f32_16x16x32_bf16(af[i], bfr[j],
                                                              acc[i][j], 0, 0, 0);
    }
    __syncthreads();
  }

#pragma unroll
  for (int i = 0; i < 4; i++)
#pragma unroll
    for (int j = 0; j < 2; j++)
#pragma unroll
      for (int r = 0; r < 4; r++) {
        int grow = m0 + wm * 64 + i * 16 + qd * 4 + r;
        int gcol = n0 + wn * 32 + j * 16 + ln;
        out[(size_t)grow * Cdim + gcol] = acc[i][j][r] + bo[gcol];
      }
}

// ---------------------------------------------------------------------------
// Flash-style Gumbel attention, shift-free softmax, key-split by KSPLIT.
// R13: back to the R5/R11 single-buffer structure (dbuf cost occupancy:
// 46 KB -> 3 blocks/CU, attn 303 -> 314; reverted).  launch_bounds(256,6):
// occupancy probe -- measured residency pinned at ~3.35 blocks/CU although
// LDS (27.6 KB -> 5) and VGPR (56 -> 8 waves/SIMD) allow more; the min-waves
// hint is the remaining suspect.  VGPR cap 512/6 = 85 >= 56 used, no spill.
// Per ktile: K,V prefetched into registers one iteration ahead. K staged
// row-major in LDS; V staged transposed with XOR-swizzled key-blocks.
// p = exp2(s) * (-rcp(log2 u)); scale*log2e pre-folded into Q; global ln2
// cancels in o/l.  Threefry software-pipelined one tile ahead; row-sum l
// via all-ones-B MFMA.
// ---------------------------------------------------------------------------
__global__ __launch_bounds__(256, 6)
void attn_kernel(const bf16_t* __restrict__ qb, const bf16_t* __restrict__ kb,
                 const bf16_t* __restrict__ vb, bf16_t* __restrict__ part_o,
                 float* __restrict__ part_l) {
  __shared__ bf16_t Ks[64 * 72];
  __shared__ bf16_t Vt[64 * 72];
  __shared__ bf16_t Ps[64 * 72];

  const int t = threadIdx.x;
  const int wave = t >> 6, lane = t & 63;
  const int ln = lane & 15, qd = lane >> 4;
  const int qtile = blockIdx.x;    // 0..31
  const int bh = blockIdx.y;       // 0..31
  const int z = blockIdx.z;        // 0..KSPLIT-1
  const int qbase = qtile * 64;
  const int kt_lo = z * (Ndim / 64 / KSPLIT);
  const int kt_hi = kt_lo + (Ndim / 64 / KSPLIT);

  const bf16_t* Qg = qb + (size_t)bh * Ndim * Ddim;
  const bf16_t* Kg = kb + (size_t)bh * Ndim * Ddim;
  const bf16_t* Vg = vb + (size_t)bh * Ndim * Ddim;

  // Q A-fragments in registers: rows wave*16+ln, cols ks*32+qd*8..+8
  const bf16_t* Qrow = Qg + (size_t)(qbase + wave * 16 + ln) * Ddim;
  bf16x8 qf0 = *(const bf16x8*)&Qrow[qd * 8];
  bf16x8 qf1 = *(const bf16x8*)&Qrow[32 + qd * 8];

  // all-ones B fragment for the l row-sum MFMA
  const bf16_t one_h = (bf16_t)1.0f;
  bf16x8 ones;
#pragma unroll
  for (int i = 0; i < 8; i++) ones[i] = one_h;

  // per-thread staging coordinates (2 x 16B chunks cover 64x64 tile)
  const int row0 = t >> 3,        c80 = (t & 7) * 8;
  const int row1 = (256 + t) >> 3, c81 = ((256 + t) & 7) * 8;
  const int swz0 = ((row0 >> 3) ^ (c80 >> 3)) * 8 + (row0 & 7);
  const int swz1 = ((row1 >> 3) ^ (c81 >> 3)) * 8 + (row1 & 7);

  // prefetch first tile into registers
  bf16x8 kr0 = *(const bf16x8*)&Kg[(size_t)(kt_lo * 64 + row0) * Ddim + c80];
  bf16x8 kr1 = *(const bf16x8*)&Kg[(size_t)(kt_lo * 64 + row1) * Ddim + c81];
  bf16x8 vr0 = *(const bf16x8*)&Vg[(size_t)(kt_lo * 64 + row0) * Ddim + c80];
  bf16x8 vr1 = *(const bf16x8*)&Vg[(size_t)(kt_lo * 64 + row1) * Ddim + c81];

  f32x4 l_acc = (f32x4){0.f, 0.f, 0.f, 0.f};
  f32x4 o_acc[4];
#pragma unroll
  for (int j = 0; j < 4; j++) o_acc[j] = (f32x4){0.f, 0.f, 0.f, 0.f};

  // threefry counter base: bh<<22 | qrow<<11 | kcol, with qrow = qbase +
  // wave*16 + qd*4 (+r folded as compile-time (r<<11)), kcol = kt*64 +
  // j*16 (compile-time) + ln.  +42 pre-folds the k1 key injection.
  const uint32_t base_rc = ((uint32_t)bh << 22) +
                           ((uint32_t)(qbase + wave * 16 + qd * 4) << 11) +
                           (uint32_t)ln + 42u;

  // prologue: gumbel factors for the first tile (overlaps prefetch vmcnt)
  float pf[4][4];
  gumbel_tile(base_rc + (uint32_t)(kt_lo * 64), pf);

  for (int kt = kt_lo; kt < kt_hi; ++kt) {
    // stage current tile from registers into LDS
    *(bf16x8*)&Ks[row0 * 72 + c80] = kr0;
    *(bf16x8*)&Ks[row1 * 72 + c81] = kr1;
#pragma unroll
    for (int jj = 0; jj < 8; jj++) Vt[(c80 + jj) * 72 + swz0] = vr0[jj];
#pragma unroll
    for (int jj = 0; jj < 8; jj++) Vt[(c81 + jj) * 72 + swz1] = vr1[jj];
    __syncthreads();

    // prefetch next tile (loads stay in flight through the compute section)
    if (kt + 1 < kt_hi) {
      kr0 = *(const bf16x8*)&Kg[(size_t)((kt + 1) * 64 + row0) * Ddim + c80];
      kr1 = *(const bf16x8*)&Kg[(size_t)((kt + 1) * 64 + row1) * Ddim + c81];
      vr0 = *(const bf16x8*)&Vg[(size_t)((kt + 1) * 64 + row0) * Ddim + c80];
      vr1 = *(const bf16x8*)&Vg[(size_t)((kt + 1) * 64 + row1) * Ddim + c81];
    }

    // S tile: wave rows 16w..16w+15, cols 64 (4 j-tiles)
    f32x4 s[4];
#pragma unroll
    for (int j = 0; j < 4; j++) s[j] = (f32x4){0.f, 0.f, 0.f, 0.f};
#pragma unroll
    for (int j = 0; j < 4; j++) {
      bf16x8 bk0 = *(const bf16x8*)&Ks[(j * 16 + ln) * 72 + qd * 8];
      bf16x8 bk1 = *(const bf16x8*)&Ks[(j * 16 + ln) * 72 + 32 + qd * 8];
      s[j] = __builtin_amdgcn_mfma_f32_16x16x32_bf16(qf0, bk0, s[j], 0, 0, 0);
      s[j] = __builtin_amdgcn_mfma_f32_16x16x32_bf16(qf1, bk1, s[j], 0, 0, 0);
    }

    // finalize: p = exp2(s) * pf (pf precomputed last iteration); stage P
#pragma unroll
    for (int r = 0; r < 4; r++)
#pragma unroll
      for (int j = 0; j < 4; j++) {
        float pv = __builtin_amdgcn_exp2f(s[j][r]) * pf[r][j];
        Ps[(wave * 16 + qd * 4 + r) * 72 + j * 16 + ln] = (bf16_t)pv;
      }
    // Ps produced and consumed by the same wave -> no barrier needed

    // O += P V ; l += P 1  (A = P rows 16w.., B[n=d][k=key] from swizzled Vt)
#pragma unroll
    for (int ks = 0; ks < 2; ++ks) {
      bf16x8 af = *(const bf16x8*)&Ps[(wave * 16 + ln) * 72 + ks * 32 + qd * 8];
      l_acc = __builtin_amdgcn_mfma_f32_16x16x32_bf16(af, ones, l_acc, 0, 0, 0);
#pragma unroll
      for (int j = 0; j < 4; j++) {
        int d = j * 16 + ln;
        bf16x8 bv8 = *(const bf16x8*)&Vt[d * 72 + (((ks * 4 + qd) ^ (d >> 3)) << 3)];
        o_acc[j] = __builtin_amdgcn_mfma_f32_16x16x32_bf16(af, bv8, o_acc[j], 0, 0, 0);
      }
    }

    // pipelined threefry for the NEXT tile: data-independent VALU work that
    // absorbs PV lgkmcnt drain, prefetch vmcnt drain, and barrier skew.
    if (kt + 1 < kt_hi)
      gumbel_tile(base_rc + (uint32_t)((kt + 1) * 64), pf);

    __syncthreads();  // protect Ks/Vt before next staging
  }

  // epilogue: bf16 o-partials + f32 l-partials (l_acc identical across ln)
  const int pidx = ((bh << 5) | qtile) * KSPLIT + z;
  bf16_t* po = part_o + (size_t)pidx * 64 * 64;
  float* pl = part_l + (size_t)pidx * 64;

  if (ln == 0) {
#pragma unroll
    for (int r = 0; r < 4; r++) pl[wave * 16 + qd * 4 + r] = l_acc[r];
  }
#pragma unroll
  for (int j = 0; j < 4; j++)
#pragma unroll
    for (int r = 0; r < 4; r++) {
      int row = wave * 16 + qd * 4 + r;
      int col = j * 16 + ln;
      po[row * 64 + col] = (bf16_t)o_acc[j][r];
    }
}

// ---------------------------------------------------------------------------
extern "C" void kernel_launch(void* const* d_in, const int* in_sizes, int n_in,
                              void* d_out, int out_size, void* d_ws, size_t ws_size,
                              hipStream_t stream) {
  const float* x  = (const float*)d_in[0];
  const float* y  = (const float*)d_in[1];
  const float* z  = (const float*)d_in[2];
  const float* Wq = (const float*)d_in[3];
  const float* bq = (const float*)d_in[4];
  const float* Wk = (const float*)d_in[5];
  const float* bk = (const float*)d_in[6];
  const float* Wv = (const float*)d_in[7];
  const float* bv = (const float*)d_in[8];
  const float* Wo = (const float*)d_in[9];
  const float* bo = (const float*)d_in[10];
  float* out = (float*)d_out;

  bf16_t* base = (bf16_t*)d_ws;
  const size_t NBIG = (size_t)Bdim * Ndim * Cdim;  // 4194304
  bf16_t* qb  = base;
  bf16_t* kb  = qb + NBIG;
  bf16_t* vb  = kb + NBIG;
  bf16_t* part_o = vb + NBIG;                       // 1024*KSPLIT*4096 bf16
  float* part_l = (float*)(part_o + (size_t)1024 * KSPLIT * 64 * 64);

  qkv_gemm_kernel<<<dim3(Cdim / 128, (Bdim * Ndim) / 128, 3), 256, 0, stream>>>(
      x, y, z, Wq, Wk, Wv, bq, bk, bv, qb, kb, vb);

  attn_kernel<<<dim3(Ndim / 64, Bdim * Hdim, KSPLIT), 256, 0, stream>>>(
      qb, kb, vb, part_o, part_l);

  out_gemm_kernel<<<dim3(Cdim / 64, (Bdim * Ndim) / 128), 256, 0, stream>>>(
      part_o, part_l, Wo, bo, out);
}

// Round 8
// 433.020 us; speedup vs baseline: 1.0778x; 1.0778x over previous
//
#include <hip/hip_runtime.h>
#include <hip/hip_bf16.h>
#include <stdint.h>

#define Bdim 4
#define Hdim 8
#define Ndim 2048
#define Cdim 512
#define Ddim 64
#define SCALE_F 0.125f
#define LOG2E 1.44269504f
// Q pre-scale folds softmax scale AND log2(e) so attn uses exp2(s) directly.
#define QSCALE_F (SCALE_F * LOG2E)

typedef __bf16 bf16_t;
typedef __bf16 bf16x8 __attribute__((ext_vector_type(8)));
typedef float f32x4 __attribute__((ext_vector_type(4)));

// ---------------------------------------------------------------------------
// Gumbel factors: JAX threefry2x32, key (0,42), partitionable path:
// counter words (hi=0, lo=flat), bits32 = out0 ^ out1.  Round-major SoA
// (16 streams advance together).  u = bitcast(bits>>9 | 0x3f800000) - 1
// (tiny dropped: only matters for bits>>9==0, ~16 of 134M elems -> <1e-4).
// Softmax identity: exp(s+g) = exp(s)/(-ln u); global ln2 cancels in o/l.
// pf = -rcp(log2(u)).  Mantissa insert via single v_alignbit_b32.
// Stream i = r*4+j has counter base + (r<<11) + j*16 (+42 prefolded).
// ---------------------------------------------------------------------------
__device__ __forceinline__ void gumbel_tile(uint32_t base, float (&pf)[4][4]) {
  const uint32_t k1 = 42u, k2 = 0x1BD11BDAu ^ 42u;
  uint32_t s0[16], s1[16];
#pragma unroll
  for (int i = 0; i < 16; i++) {
    s0[i] = 0u;
    s1[i] = base + ((uint32_t)(i >> 2) << 11) + (uint32_t)((i & 3) * 16);
  }
#define TF_RND(rot)                                                    \
  {                                                                    \
    _Pragma("unroll") for (int i = 0; i < 16; i++) {                   \
      s0[i] += s1[i];                                                  \
      s1[i] = __builtin_rotateleft32(s1[i], (rot)) ^ s0[i];            \
    }                                                                  \
  }
#define TF_INJ(a, b)                                                   \
  {                                                                    \
    _Pragma("unroll") for (int i = 0; i < 16; i++) {                   \
      s0[i] += (a);                                                    \
      s1[i] += (b);                                                    \
    }                                                                  \
  }
#define TF_INJ1(b)                                                     \
  {                                                                    \
    _Pragma("unroll") for (int i = 0; i < 16; i++) { s1[i] += (b); }   \
  }
  TF_RND(13) TF_RND(15) TF_RND(26) TF_RND(6)
  TF_INJ(k1, k2 + 1u)
  TF_RND(17) TF_RND(29) TF_RND(16) TF_RND(24)
  TF_INJ(k2, 2u)
  TF_RND(13) TF_RND(15) TF_RND(26) TF_RND(6)
  TF_INJ1(k1 + 3u)                       // x0 += k0 == 0
  TF_RND(17) TF_RND(29) TF_RND(16) TF_RND(24)
  TF_INJ(k1, k2 + 4u)
  TF_RND(13) TF_RND(15) TF_RND(26) TF_RND(6)
  TF_INJ(k2, 5u)
#undef TF_RND
#undef TF_INJ
#undef TF_INJ1
#pragma unroll
  for (int i = 0; i < 16; i++) {
    uint32_t bits = s0[i] ^ s1[i];       // partitionable 32-bit fold
    uint32_t mant;                       // (0x7F<<23) | (bits>>9) in one op
    asm("v_alignbit_b32 %0, %1, %2, 9" : "=v"(mant) : "s"(127u), "v"(bits));
    float u = __uint_as_float(mant) - 1.0f;
    pf[i >> 2][i & 3] = -__builtin_amdgcn_rcpf(__builtin_amdgcn_logf(u));
  }
}

// ---------------------------------------------------------------------------
// fp32 -> bf16x8 staging helper (RNE casts + single b128 LDS write)
// ---------------------------------------------------------------------------
__device__ __forceinline__ void stage8_f32(bf16_t* dst, const float* src) {
  float4 a0 = *(const float4*)src;
  float4 a1 = *(const float4*)(src + 4);
  union { bf16_t h[8]; uint4 u; } pk;
  pk.h[0] = (bf16_t)a0.x; pk.h[1] = (bf16_t)a0.y;
  pk.h[2] = (bf16_t)a0.z; pk.h[3] = (bf16_t)a0.w;
  pk.h[4] = (bf16_t)a1.x; pk.h[5] = (bf16_t)a1.y;
  pk.h[6] = (bf16_t)a1.z; pk.h[7] = (bf16_t)a1.w;
  *(uint4*)dst = pk.u;
}

// ---------------------------------------------------------------------------
// NT GEMM core: C[m][n] = sum_k A[m0+m][k] * W[n0+n][k], K = 512.
// Block 256 thr = 4 waves (2x2), each wave 64x64. Tiles 128x128, BK = 64.
// mfma_f32_16x16x32_bf16: A/B frag [row=lane&15][k=quad*8+j], C/D row=quad*4+r.
// fp32 sources converted to bf16 during staging (no separate cvt kernels).
// ---------------------------------------------------------------------------
template <bool AF32, bool WF32>
__device__ __forceinline__ void gemm_core_t(const void* __restrict__ Av,
                                            const void* __restrict__ Wv,
                                            int m0, int n0,
                                            bf16_t* As, bf16_t* Ws,
                                            f32x4 (&acc)[4][4]) {
  const int t = threadIdx.x;
  const int wave = t >> 6, lane = t & 63;
  const int ln = lane & 15, qd = lane >> 4;
  const int wm = wave >> 1, wn = wave & 1;

#pragma unroll
  for (int i = 0; i < 4; i++)
#pragma unroll
    for (int j = 0; j < 4; j++) acc[i][j] = (f32x4){0.f, 0.f, 0.f, 0.f};

  for (int kt = 0; kt < Cdim / 64; ++kt) {
#pragma unroll
    for (int it = 0; it < 4; ++it) {
      int vec = it * 256 + t;
      int row = vec >> 3, c8 = (vec & 7) * 8;
      if constexpr (AF32)
        stage8_f32(&As[row * 72 + c8],
                   (const float*)Av + (size_t)(m0 + row) * Cdim + kt * 64 + c8);
      else
        *(bf16x8*)&As[row * 72 + c8] =
            *((const bf16x8*)Av + ((size_t)(m0 + row) * Cdim + kt * 64 + c8) / 8);
      if constexpr (WF32)
        stage8_f32(&Ws[row * 72 + c8],
                   (const float*)Wv + (size_t)(n0 + row) * Cdim + kt * 64 + c8);
      else
        *(bf16x8*)&Ws[row * 72 + c8] =
            *((const bf16x8*)Wv + ((size_t)(n0 + row) * Cdim + kt * 64 + c8) / 8);
    }
    __syncthreads();
#pragma unroll
    for (int ks = 0; ks < 2; ++ks) {
      bf16x8 af[4], bfr[4];
#pragma unroll
      for (int i = 0; i < 4; i++)
        af[i] = *(const bf16x8*)&As[(wm * 64 + i * 16 + ln) * 72 + ks * 32 + qd * 8];
#pragma unroll
      for (int j = 0; j < 4; j++)
        bfr[j] = *(const bf16x8*)&Ws[(wn * 64 + j * 16 + ln) * 72 + ks * 32 + qd * 8];
#pragma unroll
      for (int i = 0; i < 4; i++)
#pragma unroll
        for (int j = 0; j < 4; j++)
          acc[i][j] = __builtin_amdgcn_mfma_f32_16x16x32_bf16(af[i], bfr[j],
                                                              acc[i][j], 0, 0, 0);
    }
    __syncthreads();
  }
}

// QKV projections fused over blockIdx.z; epilogue scatters to [B,H,L,D] bf16.
// Q (sel==0) is pre-scaled by SCALE*LOG2E so attn uses exp2(s) with no mul.
__global__ __launch_bounds__(256, 3)
void qkv_gemm_kernel(const float* __restrict__ x, const float* __restrict__ y,
                     const float* __restrict__ z, const float* __restrict__ Wq,
                     const float* __restrict__ Wk, const float* __restrict__ Wv,
                     const float* __restrict__ bq, const float* __restrict__ bk,
                     const float* __restrict__ bv, bf16_t* __restrict__ qo,
                     bf16_t* __restrict__ ko, bf16_t* __restrict__ vo) {
  __shared__ bf16_t As[128 * 72];
  __shared__ bf16_t Ws[128 * 72];
  const int sel = blockIdx.z;
  const float* A = sel == 0 ? x : (sel == 1 ? y : z);
  const float* W = sel == 0 ? Wq : (sel == 1 ? Wk : Wv);
  const float* bias = sel == 0 ? bq : (sel == 1 ? bk : bv);
  bf16_t* O = sel == 0 ? qo : (sel == 1 ? ko : vo);
  const float mul = sel == 0 ? QSCALE_F : 1.0f;
  const int m0 = blockIdx.y * 128, n0 = blockIdx.x * 128;

  f32x4 acc[4][4];
  gemm_core_t<true, true>(A, W, m0, n0, As, Ws, acc);

  const int t = threadIdx.x;
  const int wave = t >> 6, lane = t & 63;
  const int ln = lane & 15, qd = lane >> 4;
  const int wm = wave >> 1, wn = wave & 1;
#pragma unroll
  for (int i = 0; i < 4; i++)
#pragma unroll
    for (int j = 0; j < 4; j++)
#pragma unroll
      for (int r = 0; r < 4; r++) {
        int grow = m0 + wm * 64 + i * 16 + qd * 4 + r;
        int gcol = n0 + wn * 64 + j * 16 + ln;
        float val = (acc[i][j][r] + bias[gcol]) * mul;
        int b = grow >> 11, n = grow & 2047;
        int h = gcol >> 6, d = gcol & 63;
        O[(((size_t)b * Hdim + h) * Ndim + n) * Ddim + d] = (bf16_t)val;
      }
}

// ---------------------------------------------------------------------------
// Output projection: ab[8192,512] bf16 @ Wo^T (fp32, staged-cvt) + bo.
// Tile 128(M) x 64(N) -> 512 blocks, 2 blocks/CU, 4 waves (2x2), wave=64x32.
// (R6-measured config; R7's fused combine redid combine work 8x -- reverted.)
// ---------------------------------------------------------------------------
__global__ __launch_bounds__(256, 4)
void out_gemm_kernel(const bf16_t* __restrict__ ab, const float* __restrict__ Wo,
                     const float* __restrict__ bo, float* __restrict__ out) {
  __shared__ bf16_t As[128 * 72];
  __shared__ bf16_t Ws[64 * 72];
  const int t = threadIdx.x;
  const int wave = t >> 6, lane = t & 63;
  const int ln = lane & 15, qd = lane >> 4;
  const int wm = wave >> 1, wn = wave & 1;
  const int m0 = blockIdx.y * 128, n0 = blockIdx.x * 64;

  f32x4 acc[4][2];
#pragma unroll
  for (int i = 0; i < 4; i++)
#pragma unroll
    for (int j = 0; j < 2; j++) acc[i][j] = (f32x4){0.f, 0.f, 0.f, 0.f};

  for (int kt = 0; kt < Cdim / 64; ++kt) {
#pragma unroll
    for (int it = 0; it < 4; ++it) {
      int vec = it * 256 + t;
      int row = vec >> 3, c8 = (vec & 7) * 8;
      *(bf16x8*)&As[row * 72 + c8] =
          *(const bf16x8*)&ab[(size_t)(m0 + row) * Cdim + kt * 64 + c8];
    }
#pragma unroll
    for (int it = 0; it < 2; ++it) {
      int vec = it * 256 + t;
      int row = vec >> 3, c8 = (vec & 7) * 8;
      stage8_f32(&Ws[row * 72 + c8],
                 Wo + (size_t)(n0 + row) * Cdim + kt * 64 + c8);
    }
    __syncthreads();
#pragma unroll
    for (int ks = 0; ks < 2; ++ks) {
      bf16x8 af[4], bfr[2];
#pragma unroll
      for (int i = 0; i < 4; i++)
        af[i] = *(const bf16x8*)&As[(wm * 64 + i * 16 + ln) * 72 + ks * 32 + qd * 8];
#pragma unroll
      for (int j = 0; j < 2; j++)
        bfr[j] = *(const bf16x8*)&Ws[(wn * 32 + j * 16 + ln) * 72 + ks * 32 + qd * 8];
#pragma unroll
      for (int i = 0; i < 4; i++)
#pragma unroll
        for (int j = 0; j < 2; j++)
          acc[i][j] = __builtin_amdgcn_mfma_f32_16x16x32_bf16(af[i], bfr[j],
                                                              acc[i][j], 0, 0, 0);
    }
    __syncthreads();
  }

#pragma unroll
  for (int i = 0; i < 4; i++)
#pragma unroll
    for (int j = 0; j < 2; j++)
#pragma unroll
      for (int r = 0; r < 4; r++) {
        int grow = m0 + wm * 64 + i * 16 + qd * 4 + r;
        int gcol = n0 + wn * 32 + j * 16 + ln;
        out[(size_t)grow * Cdim + gcol] = acc[i][j][r] + bo[gcol];
      }
}

// ---------------------------------------------------------------------------
// Flash-style Gumbel attention, shift-free softmax.
// R14: NO KSPLIT -- grid is exactly (32 qtiles x 32 bh) = 1024 blocks =
// 4 blocks/CU, all resident from t=0 (zero dispatch rounds, zero tail,
// identical per-block work).  Each block walks all 32 ktiles, accumulating
// o in f32 the whole way (more accurate than the old bf16 partial sums),
// applies 1/l in the epilogue and writes ab[B,N,C] directly -- the combine
// kernel and part_o/part_l round-trip are deleted.
// Per ktile: K,V prefetched into registers one iteration ahead. K staged
// row-major in LDS; V staged transposed with XOR-swizzled key-blocks.
// p = exp2(s) * (-rcp(log2 u)); scale*log2e pre-folded into Q; global ln2
// cancels in o/l.  Threefry software-pipelined one tile ahead; row-sum l
// via all-ones-B MFMA.
// ---------------------------------------------------------------------------
__global__ __launch_bounds__(256, 4)
void attn_kernel(const bf16_t* __restrict__ qb, const bf16_t* __restrict__ kb,
                 const bf16_t* __restrict__ vb, bf16_t* __restrict__ ab) {
  __shared__ bf16_t Ks[64 * 72];
  __shared__ bf16_t Vt[64 * 72];
  __shared__ bf16_t Ps[64 * 72];

  const int t = threadIdx.x;
  const int wave = t >> 6, lane = t & 63;
  const int ln = lane & 15, qd = lane >> 4;
  const int qtile = blockIdx.x;    // 0..31
  const int bh = blockIdx.y;       // 0..31
  const int qbase = qtile * 64;
  const int NT = Ndim / 64;        // 32 ktiles, full key range

  const bf16_t* Qg = qb + (size_t)bh * Ndim * Ddim;
  const bf16_t* Kg = kb + (size_t)bh * Ndim * Ddim;
  const bf16_t* Vg = vb + (size_t)bh * Ndim * Ddim;

  // Q A-fragments in registers: rows wave*16+ln, cols ks*32+qd*8..+8
  const bf16_t* Qrow = Qg + (size_t)(qbase + wave * 16 + ln) * Ddim;
  bf16x8 qf0 = *(const bf16x8*)&Qrow[qd * 8];
  bf16x8 qf1 = *(const bf16x8*)&Qrow[32 + qd * 8];

  // all-ones B fragment for the l row-sum MFMA
  const bf16_t one_h = (bf16_t)1.0f;
  bf16x8 ones;
#pragma unroll
  for (int i = 0; i < 8; i++) ones[i] = one_h;

  // per-thread staging coordinates (2 x 16B chunks cover 64x64 tile)
  const int row0 = t >> 3,        c80 = (t & 7) * 8;
  const int row1 = (256 + t) >> 3, c81 = ((256 + t) & 7) * 8;
  const int swz0 = ((row0 >> 3) ^ (c80 >> 3)) * 8 + (row0 & 7);
  const int swz1 = ((row1 >> 3) ^ (c81 >> 3)) * 8 + (row1 & 7);

  // prefetch first tile into registers
  bf16x8 kr0 = *(const bf16x8*)&Kg[(size_t)(row0)*Ddim + c80];
  bf16x8 kr1 = *(const bf16x8*)&Kg[(size_t)(row1)*Ddim + c81];
  bf16x8 vr0 = *(const bf16x8*)&Vg[(size_t)(row0)*Ddim + c80];
  bf16x8 vr1 = *(const bf16x8*)&Vg[(size_t)(row1)*Ddim + c81];

  f32x4 l_acc = (f32x4){0.f, 0.f, 0.f, 0.f};
  f32x4 o_acc[4];
#pragma unroll
  for (int j = 0; j < 4; j++) o_acc[j] = (f32x4){0.f, 0.f, 0.f, 0.f};

  // threefry counter base: bh<<22 | qrow<<11 | kcol, with qrow = qbase +
  // wave*16 + qd*4 (+r folded as compile-time (r<<11)), kcol = kt*64 +
  // j*16 (compile-time) + ln.  +42 pre-folds the k1 key injection.
  const uint32_t base_rc = ((uint32_t)bh << 22) +
                           ((uint32_t)(qbase + wave * 16 + qd * 4) << 11) +
                           (uint32_t)ln + 42u;

  // prologue: gumbel factors for the first tile (overlaps prefetch vmcnt)
  float pf[4][4];
  gumbel_tile(base_rc, pf);

  for (int kt = 0; kt < NT; ++kt) {
    // stage current tile from registers into LDS
    *(bf16x8*)&Ks[row0 * 72 + c80] = kr0;
    *(bf16x8*)&Ks[row1 * 72 + c81] = kr1;
#pragma unroll
    for (int jj = 0; jj < 8; jj++) Vt[(c80 + jj) * 72 + swz0] = vr0[jj];
#pragma unroll
    for (int jj = 0; jj < 8; jj++) Vt[(c81 + jj) * 72 + swz1] = vr1[jj];
    __syncthreads();

    // prefetch next tile (loads stay in flight through the compute section)
    if (kt + 1 < NT) {
      kr0 = *(const bf16x8*)&Kg[(size_t)((kt + 1) * 64 + row0) * Ddim + c80];
      kr1 = *(const bf16x8*)&Kg[(size_t)((kt + 1) * 64 + row1) * Ddim + c81];
      vr0 = *(const bf16x8*)&Vg[(size_t)((kt + 1) * 64 + row0) * Ddim + c80];
      vr1 = *(const bf16x8*)&Vg[(size_t)((kt + 1) * 64 + row1) * Ddim + c81];
    }

    // S tile: wave rows 16w..16w+15, cols 64 (4 j-tiles)
    f32x4 s[4];
#pragma unroll
    for (int j = 0; j < 4; j++) s[j] = (f32x4){0.f, 0.f, 0.f, 0.f};
#pragma unroll
    for (int j = 0; j < 4; j++) {
      bf16x8 bk0 = *(const bf16x8*)&Ks[(j * 16 + ln) * 72 + qd * 8];
      bf16x8 bk1 = *(const bf16x8*)&Ks[(j * 16 + ln) * 72 + 32 + qd * 8];
      s[j] = __builtin_amdgcn_mfma_f32_16x16x32_bf16(qf0, bk0, s[j], 0, 0, 0);
      s[j] = __builtin_amdgcn_mfma_f32_16x16x32_bf16(qf1, bk1, s[j], 0, 0, 0);
    }

    // finalize: p = exp2(s) * pf (pf precomputed last iteration); stage P
#pragma unroll
    for (int r = 0; r < 4; r++)
#pragma unroll
      for (int j = 0; j < 4; j++) {
        float pv = __builtin_amdgcn_exp2f(s[j][r]) * pf[r][j];
        Ps[(wave * 16 + qd * 4 + r) * 72 + j * 16 + ln] = (bf16_t)pv;
      }
    // Ps produced and consumed by the same wave -> no barrier needed

    // O += P V ; l += P 1  (A = P rows 16w.., B[n=d][k=key] from swizzled Vt)
#pragma unroll
    for (int ks = 0; ks < 2; ++ks) {
      bf16x8 af = *(const bf16x8*)&Ps[(wave * 16 + ln) * 72 + ks * 32 + qd * 8];
      l_acc = __builtin_amdgcn_mfma_f32_16x16x32_bf16(af, ones, l_acc, 0, 0, 0);
#pragma unroll
      for (int j = 0; j < 4; j++) {
        int d = j * 16 + ln;
        bf16x8 bv8 = *(const bf16x8*)&Vt[d * 72 + (((ks * 4 + qd) ^ (d >> 3)) << 3)];
        o_acc[j] = __builtin_amdgcn_mfma_f32_16x16x32_bf16(af, bv8, o_acc[j], 0, 0, 0);
      }
    }

    // pipelined threefry for the NEXT tile: data-independent VALU work that
    // absorbs PV lgkmcnt drain, prefetch vmcnt drain, and barrier skew.
    if (kt + 1 < NT)
      gumbel_tile(base_rc + (uint32_t)((kt + 1) * 64), pf);

    __syncthreads();  // protect Ks/Vt before next staging
  }

  // epilogue: o/l -> bf16 ab[b][n][h*64+d]  (l_acc identical across ln)
  const int b = bh >> 3, h = bh & 7;
#pragma unroll
  for (int r = 0; r < 4; r++) {
    const int n = qbase + wave * 16 + qd * 4 + r;
    const float linv = 1.0f / l_acc[r];
    bf16_t* dst = ab + ((size_t)b * Ndim + n) * Cdim + h * 64;
#pragma unroll
    for (int j = 0; j < 4; j++)
      dst[j * 16 + ln] = (bf16_t)(o_acc[j][r] * linv);
  }
}

// ---------------------------------------------------------------------------
extern "C" void kernel_launch(void* const* d_in, const int* in_sizes, int n_in,
                              void* d_out, int out_size, void* d_ws, size_t ws_size,
                              hipStream_t stream) {
  const float* x  = (const float*)d_in[0];
  const float* y  = (const float*)d_in[1];
  const float* z  = (const float*)d_in[2];
  const float* Wq = (const float*)d_in[3];
  const float* bq = (const float*)d_in[4];
  const float* Wk = (const float*)d_in[5];
  const float* bk = (const float*)d_in[6];
  const float* Wv = (const float*)d_in[7];
  const float* bv = (const float*)d_in[8];
  const float* Wo = (const float*)d_in[9];
  const float* bo = (const float*)d_in[10];
  float* out = (float*)d_out;

  bf16_t* base = (bf16_t*)d_ws;
  const size_t NBIG = (size_t)Bdim * Ndim * Cdim;  // 4194304
  bf16_t* qb = base;
  bf16_t* kb = qb + NBIG;
  bf16_t* vb = kb + NBIG;
  bf16_t* ab = vb + NBIG;

  qkv_gemm_kernel<<<dim3(Cdim / 128, (Bdim * Ndim) / 128, 3), 256, 0, stream>>>(
      x, y, z, Wq, Wk, Wv, bq, bk, bv, qb, kb, vb);

  attn_kernel<<<dim3(Ndim / 64, Bdim * Hdim), 256, 0, stream>>>(qb, kb, vb, ab);

  out_gemm_kernel<<<dim3(Cdim / 64, (Bdim * Ndim) / 128), 256, 0, stream>>>(
      ab, Wo, bo, out);
}

// Round 10
// 431.658 us; speedup vs baseline: 1.0812x; 1.0032x over previous
//
#include <hip/hip_runtime.h>
#include <hip/hip_bf16.h>
#include <stdint.h>

#define Bdim 4
#define Hdim 8
#define Ndim 2048
#define Cdim 512
#define Ddim 64
#define SCALE_F 0.125f
#define KSPLIT 4
#define LOG2E 1.44269504f
// Q pre-scale folds softmax scale AND log2(e) so attn uses exp2(s) directly.
#define QSCALE_F (SCALE_F * LOG2E)

typedef __bf16 bf16_t;
typedef __bf16 bf16x8 __attribute__((ext_vector_type(8)));
typedef float f32x4 __attribute__((ext_vector_type(4)));

// ---------------------------------------------------------------------------
// Gumbel factors: JAX threefry2x32, key (0,42), partitionable path:
// counter words (hi=0, lo=flat), bits32 = out0 ^ out1.  Round-major SoA
// (16 streams advance together).  u = bitcast(bits>>9 | 0x3f800000) - 1
// (tiny dropped: only matters for bits>>9==0, ~16 of 134M elems -> <1e-4).
// Softmax identity: exp(s+g) = exp(s)/(-ln u); global ln2 cancels in o/l.
// pf = -rcp(log2(u)).  Mantissa insert via single v_alignbit_b32.
// Stream i = r*4+j has counter base + (r<<11) + j*16 (+42 prefolded).
// ---------------------------------------------------------------------------
__device__ __forceinline__ void gumbel_tile(uint32_t base, float (&pf)[4][4]) {
  const uint32_t k1 = 42u, k2 = 0x1BD11BDAu ^ 42u;
  uint32_t s0[16], s1[16];
#pragma unroll
  for (int i = 0; i < 16; i++) {
    s0[i] = 0u;
    s1[i] = base + ((uint32_t)(i >> 2) << 11) + (uint32_t)((i & 3) * 16);
  }
#define TF_RND(rot)                                                    \
  {                                                                    \
    _Pragma("unroll") for (int i = 0; i < 16; i++) {                   \
      s0[i] += s1[i];                                                  \
      s1[i] = __builtin_rotateleft32(s1[i], (rot)) ^ s0[i];            \
    }                                                                  \
  }
#define TF_INJ(a, b)                                                   \
  {                                                                    \
    _Pragma("unroll") for (int i = 0; i < 16; i++) {                   \
      s0[i] += (a);                                                    \
      s1[i] += (b);                                                    \
    }                                                                  \
  }
#define TF_INJ1(b)                                                     \
  {                                                                    \
    _Pragma("unroll") for (int i = 0; i < 16; i++) { s1[i] += (b); }   \
  }
  TF_RND(13) TF_RND(15) TF_RND(26) TF_RND(6)
  TF_INJ(k1, k2 + 1u)
  TF_RND(17) TF_RND(29) TF_RND(16) TF_RND(24)
  TF_INJ(k2, 2u)
  TF_RND(13) TF_RND(15) TF_RND(26) TF_RND(6)
  TF_INJ1(k1 + 3u)                       // x0 += k0 == 0
  TF_RND(17) TF_RND(29) TF_RND(16) TF_RND(24)
  TF_INJ(k1, k2 + 4u)
  TF_RND(13) TF_RND(15) TF_RND(26) TF_RND(6)
  TF_INJ(k2, 5u)
#undef TF_RND
#undef TF_INJ
#undef TF_INJ1
#pragma unroll
  for (int i = 0; i < 16; i++) {
    uint32_t bits = s0[i] ^ s1[i];       // partitionable 32-bit fold
    uint32_t mant;                       // (0x7F<<23) | (bits>>9) in one op
    asm("v_alignbit_b32 %0, %1, %2, 9" : "=v"(mant) : "s"(127u), "v"(bits));
    float u = __uint_as_float(mant) - 1.0f;
    pf[i >> 2][i & 3] = -__builtin_amdgcn_rcpf(__builtin_amdgcn_logf(u));
  }
}

// ---------------------------------------------------------------------------
// fp32 -> bf16x8 staging helper (RNE casts + single b128 LDS write)
// ---------------------------------------------------------------------------
__device__ __forceinline__ void stage8_f32(bf16_t* dst, const float* src) {
  float4 a0 = *(const float4*)src;
  float4 a1 = *(const float4*)(src + 4);
  union { bf16_t h[8]; uint4 u; } pk;
  pk.h[0] = (bf16_t)a0.x; pk.h[1] = (bf16_t)a0.y;
  pk.h[2] = (bf16_t)a0.z; pk.h[3] = (bf16_t)a0.w;
  pk.h[4] = (bf16_t)a1.x; pk.h[5] = (bf16_t)a1.y;
  pk.h[6] = (bf16_t)a1.z; pk.h[7] = (bf16_t)a1.w;
  *(uint4*)dst = pk.u;
}

// ---------------------------------------------------------------------------
// NT GEMM core: C[m][n] = sum_k A[m0+m][k] * W[n0+n][k], K = 512.
// Block 256 thr = 4 waves (2x2), each wave 64x64. Tiles 128x128, BK = 64.
// mfma_f32_16x16x32_bf16: A/B frag [row=lane&15][k=quad*8+j], C/D row=quad*4+r.
// fp32 sources converted to bf16 during staging (no separate cvt kernels).
// ---------------------------------------------------------------------------
template <bool AF32, bool WF32>
__device__ __forceinline__ void gemm_core_t(const void* __restrict__ Av,
                                            const void* __restrict__ Wv,
                                            int m0, int n0,
                                            bf16_t* As, bf16_t* Ws,
                                            f32x4 (&acc)[4][4]) {
  const int t = threadIdx.x;
  const int wave = t >> 6, lane = t & 63;
  const int ln = lane & 15, qd = lane >> 4;
  const int wm = wave >> 1, wn = wave & 1;

#pragma unroll
  for (int i = 0; i < 4; i++)
#pragma unroll
    for (int j = 0; j < 4; j++) acc[i][j] = (f32x4){0.f, 0.f, 0.f, 0.f};

  for (int kt = 0; kt < Cdim / 64; ++kt) {
#pragma unroll
    for (int it = 0; it < 4; ++it) {
      int vec = it * 256 + t;
      int row = vec >> 3, c8 = (vec & 7) * 8;
      if constexpr (AF32)
        stage8_f32(&As[row * 72 + c8],
                   (const float*)Av + (size_t)(m0 + row) * Cdim + kt * 64 + c8);
      else
        *(bf16x8*)&As[row * 72 + c8] =
            *((const bf16x8*)Av + ((size_t)(m0 + row) * Cdim + kt * 64 + c8) / 8);
      if constexpr (WF32)
        stage8_f32(&Ws[row * 72 + c8],
                   (const float*)Wv + (size_t)(n0 + row) * Cdim + kt * 64 + c8);
      else
        *(bf16x8*)&Ws[row * 72 + c8] =
            *((const bf16x8*)Wv + ((size_t)(n0 + row) * Cdim + kt * 64 + c8) / 8);
    }
    __syncthreads();
#pragma unroll
    for (int ks = 0; ks < 2; ++ks) {
      bf16x8 af[4], bfr[4];
#pragma unroll
      for (int i = 0; i < 4; i++)
        af[i] = *(const bf16x8*)&As[(wm * 64 + i * 16 + ln) * 72 + ks * 32 + qd * 8];
#pragma unroll
      for (int j = 0; j < 4; j++)
        bfr[j] = *(const bf16x8*)&Ws[(wn * 64 + j * 16 + ln) * 72 + ks * 32 + qd * 8];
#pragma unroll
      for (int i = 0; i < 4; i++)
#pragma unroll
        for (int j = 0; j < 4; j++)
          acc[i][j] = __builtin_amdgcn_mfma_f32_16x16x32_bf16(af[i], bfr[j],
                                                              acc[i][j], 0, 0, 0);
    }
    __syncthreads();
  }
}

// QKV projections fused over blockIdx.z; epilogue scatters to [B,H,L,D] bf16.
// Q (sel==0) is pre-scaled by SCALE*LOG2E so attn uses exp2(s) with no mul.
__global__ __launch_bounds__(256, 3)
void qkv_gemm_kernel(const float* __restrict__ x, const float* __restrict__ y,
                     const float* __restrict__ z, const float* __restrict__ Wq,
                     const float* __restrict__ Wk, const float* __restrict__ Wv,
                     const float* __restrict__ bq, const float* __restrict__ bk,
                     const float* __restrict__ bv, bf16_t* __restrict__ qo,
                     bf16_t* __restrict__ ko, bf16_t* __restrict__ vo) {
  __shared__ bf16_t As[128 * 72];
  __shared__ bf16_t Ws[128 * 72];
  const int sel = blockIdx.z;
  const float* A = sel == 0 ? x : (sel == 1 ? y : z);
  const float* W = sel == 0 ? Wq : (sel == 1 ? Wk : Wv);
  const float* bias = sel == 0 ? bq : (sel == 1 ? bk : bv);
  bf16_t* O = sel == 0 ? qo : (sel == 1 ? ko : vo);
  const float mul = sel == 0 ? QSCALE_F : 1.0f;
  const int m0 = blockIdx.y * 128, n0 = blockIdx.x * 128;

  f32x4 acc[4][4];
  gemm_core_t<true, true>(A, W, m0, n0, As, Ws, acc);

  const int t = threadIdx.x;
  const int wave = t >> 6, lane = t & 63;
  const int ln = lane & 15, qd = lane >> 4;
  const int wm = wave >> 1, wn = wave & 1;
#pragma unroll
  for (int i = 0; i < 4; i++)
#pragma unroll
    for (int j = 0; j < 4; j++)
#pragma unroll
      for (int r = 0; r < 4; r++) {
        int grow = m0 + wm * 64 + i * 16 + qd * 4 + r;
        int gcol = n0 + wn * 64 + j * 16 + ln;
        float val = (acc[i][j][r] + bias[gcol]) * mul;
        int b = grow >> 11, n = grow & 2047;
        int h = gcol >> 6, d = gcol & 63;
        O[(((size_t)b * Hdim + h) * Ndim + n) * Ddim + d] = (bf16_t)val;
      }
}

// ---------------------------------------------------------------------------
// Output projection: ab[8192,512] bf16 @ Wo^T (fp32, staged-cvt) + bo.
// Tile 128(M) x 64(N) -> 512 blocks, 2 blocks/CU, 4 waves (2x2), wave=64x32.
// (R6/R8-measured config.)
// ---------------------------------------------------------------------------
__global__ __launch_bounds__(256, 4)
void out_gemm_kernel(const bf16_t* __restrict__ ab, const float* __restrict__ Wo,
                     const float* __restrict__ bo, float* __restrict__ out) {
  __shared__ bf16_t As[128 * 72];
  __shared__ bf16_t Ws[64 * 72];
  const int t = threadIdx.x;
  const int wave = t >> 6, lane = t & 63;
  const int ln = lane & 15, qd = lane >> 4;
  const int wm = wave >> 1, wn = wave & 1;
  const int m0 = blockIdx.y * 128, n0 = blockIdx.x * 64;

  f32x4 acc[4][2];
#pragma unroll
  for (int i = 0; i < 4; i++)
#pragma unroll
    for (int j = 0; j < 2; j++) acc[i][j] = (f32x4){0.f, 0.f, 0.f, 0.f};

  for (int kt = 0; kt < Cdim / 64; ++kt) {
#pragma unroll
    for (int it = 0; it < 4; ++it) {
      int vec = it * 256 + t;
      int row = vec >> 3, c8 = (vec & 7) * 8;
      *(bf16x8*)&As[row * 72 + c8] =
          *(const bf16x8*)&ab[(size_t)(m0 + row) * Cdim + kt * 64 + c8];
    }
#pragma unroll
    for (int it = 0; it < 2; ++it) {
      int vec = it * 256 + t;
      int row = vec >> 3, c8 = (vec & 7) * 8;
      stage8_f32(&Ws[row * 72 + c8],
                 Wo + (size_t)(n0 + row) * Cdim + kt * 64 + c8);
    }
    __syncthreads();
#pragma unroll
    for (int ks = 0; ks < 2; ++ks) {
      bf16x8 af[4], bfr[2];
#pragma unroll
      for (int i = 0; i < 4; i++)
        af[i] = *(const bf16x8*)&As[(wm * 64 + i * 16 + ln) * 72 + ks * 32 + qd * 8];
#pragma unroll
      for (int j = 0; j < 2; j++)
        bfr[j] = *(const bf16x8*)&Ws[(wn * 32 + j * 16 + ln) * 72 + ks * 32 + qd * 8];
#pragma unroll
      for (int i = 0; i < 4; i++)
#pragma unroll
        for (int j = 0; j < 2; j++)
          acc[i][j] = __builtin_amdgcn_mfma_f32_16x16x32_bf16(af[i], bfr[j],
                                                              acc[i][j], 0, 0, 0);
    }
    __syncthreads();
  }

#pragma unroll
  for (int i = 0; i < 4; i++)
#pragma unroll
    for (int j = 0; j < 2; j++)
#pragma unroll
      for (int r = 0; r < 4; r++) {
        int grow = m0 + wm * 64 + i * 16 + qd * 4 + r;
        int gcol = n0 + wn * 32 + j * 16 + ln;
        out[(size_t)grow * Cdim + gcol] = acc[i][j][r] + bo[gcol];
      }
}

// ---------------------------------------------------------------------------
// Flash-style Gumbel attention, shift-free softmax, key-split by KSPLIT.
// R15 = exact R5/R11 structure (best measured attn: 303 us, thrice).
// KSPLIT=4 -> 4096 blocks keeps ~5 blocks/CU resident (occupancy 42%);
// R8's no-split 1024-block grid dropped residency to 4 blocks/CU and cost
// +9 us.  Single-buffer K/V (dbuf cost occupancy, R6).  Per ktile: K,V
// prefetched into registers one iteration ahead. K staged row-major in LDS;
// V staged transposed with XOR-swizzled key-blocks.  p = exp2(s) *
// (-rcp(log2 u)); scale*log2e pre-folded into Q; global ln2 cancels in o/l.
// Threefry software-pipelined one tile ahead; row-sum l via all-ones MFMA.
// ---------------------------------------------------------------------------
__global__ __launch_bounds__(256, 4)
void attn_kernel(const bf16_t* __restrict__ qb, const bf16_t* __restrict__ kb,
                 const bf16_t* __restrict__ vb, bf16_t* __restrict__ part_o,
                 float* __restrict__ part_l) {
  __shared__ bf16_t Ks[64 * 72];
  __shared__ bf16_t Vt[64 * 72];
  __shared__ bf16_t Ps[64 * 72];

  const int t = threadIdx.x;
  const int wave = t >> 6, lane = t & 63;
  const int ln = lane & 15, qd = lane >> 4;
  const int qtile = blockIdx.x;    // 0..31
  const int bh = blockIdx.y;       // 0..31
  const int z = blockIdx.z;        // 0..KSPLIT-1
  const int qbase = qtile * 64;
  const int kt_lo = z * (Ndim / 64 / KSPLIT);
  const int kt_hi = kt_lo + (Ndim / 64 / KSPLIT);

  const bf16_t* Qg = qb + (size_t)bh * Ndim * Ddim;
  const bf16_t* Kg = kb + (size_t)bh * Ndim * Ddim;
  const bf16_t* Vg = vb + (size_t)bh * Ndim * Ddim;

  // Q A-fragments in registers: rows wave*16+ln, cols ks*32+qd*8..+8
  const bf16_t* Qrow = Qg + (size_t)(qbase + wave * 16 + ln) * Ddim;
  bf16x8 qf0 = *(const bf16x8*)&Qrow[qd * 8];
  bf16x8 qf1 = *(const bf16x8*)&Qrow[32 + qd * 8];

  // all-ones B fragment for the l row-sum MFMA
  const bf16_t one_h = (bf16_t)1.0f;
  bf16x8 ones;
#pragma unroll
  for (int i = 0; i < 8; i++) ones[i] = one_h;

  // per-thread staging coordinates (2 x 16B chunks cover 64x64 tile)
  const int row0 = t >> 3,        c80 = (t & 7) * 8;
  const int row1 = (256 + t) >> 3, c81 = ((256 + t) & 7) * 8;
  const int swz0 = ((row0 >> 3) ^ (c80 >> 3)) * 8 + (row0 & 7);
  const int swz1 = ((row1 >> 3) ^ (c81 >> 3)) * 8 + (row1 & 7);

  // prefetch first tile into registers
  bf16x8 kr0 = *(const bf16x8*)&Kg[(size_t)(kt_lo * 64 + row0) * Ddim + c80];
  bf16x8 kr1 = *(const bf16x8*)&Kg[(size_t)(kt_lo * 64 + row1) * Ddim + c81];
  bf16x8 vr0 = *(const bf16x8*)&Vg[(size_t)(kt_lo * 64 + row0) * Ddim + c80];
  bf16x8 vr1 = *(const bf16x8*)&Vg[(size_t)(kt_lo * 64 + row1) * Ddim + c81];

  f32x4 l_acc = (f32x4){0.f, 0.f, 0.f, 0.f};
  f32x4 o_acc[4];
#pragma unroll
  for (int j = 0; j < 4; j++) o_acc[j] = (f32x4){0.f, 0.f, 0.f, 0.f};

  // threefry counter base: bh<<22 | qrow<<11 | kcol, with qrow = qbase +
  // wave*16 + qd*4 (+r folded as compile-time (r<<11)), kcol = kt*64 +
  // j*16 (compile-time) + ln.  +42 pre-folds the k1 key injection.
  const uint32_t base_rc = ((uint32_t)bh << 22) +
                           ((uint32_t)(qbase + wave * 16 + qd * 4) << 11) +
                           (uint32_t)ln + 42u;

  // prologue: gumbel factors for the first tile (overlaps prefetch vmcnt)
  float pf[4][4];
  gumbel_tile(base_rc + (uint32_t)(kt_lo * 64), pf);

  for (int kt = kt_lo; kt < kt_hi; ++kt) {
    // stage current tile from registers into LDS
    *(bf16x8*)&Ks[row0 * 72 + c80] = kr0;
    *(bf16x8*)&Ks[row1 * 72 + c81] = kr1;
#pragma unroll
    for (int jj = 0; jj < 8; jj++) Vt[(c80 + jj) * 72 + swz0] = vr0[jj];
#pragma unroll
    for (int jj = 0; jj < 8; jj++) Vt[(c81 + jj) * 72 + swz1] = vr1[jj];
    __syncthreads();

    // prefetch next tile (loads stay in flight through the compute section)
    if (kt + 1 < kt_hi) {
      kr0 = *(const bf16x8*)&Kg[(size_t)((kt + 1) * 64 + row0) * Ddim + c80];
      kr1 = *(const bf16x8*)&Kg[(size_t)((kt + 1) * 64 + row1) * Ddim + c81];
      vr0 = *(const bf16x8*)&Vg[(size_t)((kt + 1) * 64 + row0) * Ddim + c80];
      vr1 = *(const bf16x8*)&Vg[(size_t)((kt + 1) * 64 + row1) * Ddim + c81];
    }

    // S tile: wave rows 16w..16w+15, cols 64 (4 j-tiles)
    f32x4 s[4];
#pragma unroll
    for (int j = 0; j < 4; j++) s[j] = (f32x4){0.f, 0.f, 0.f, 0.f};
#pragma unroll
    for (int j = 0; j < 4; j++) {
      bf16x8 bk0 = *(const bf16x8*)&Ks[(j * 16 + ln) * 72 + qd * 8];
      bf16x8 bk1 = *(const bf16x8*)&Ks[(j * 16 + ln) * 72 + 32 + qd * 8];
      s[j] = __builtin_amdgcn_mfma_f32_16x16x32_bf16(qf0, bk0, s[j], 0, 0, 0);
      s[j] = __builtin_amdgcn_mfma_f32_16x16x32_bf16(qf1, bk1, s[j], 0, 0, 0);
    }

    // finalize: p = exp2(s) * pf (pf precomputed last iteration); stage P
#pragma unroll
    for (int r = 0; r < 4; r++)
#pragma unroll
      for (int j = 0; j < 4; j++) {
        float pv = __builtin_amdgcn_exp2f(s[j][r]) * pf[r][j];
        Ps[(wave * 16 + qd * 4 + r) * 72 + j * 16 + ln] = (bf16_t)pv;
      }
    // Ps produced and consumed by the same wave -> no barrier needed

    // O += P V ; l += P 1  (A = P rows 16w.., B[n=d][k=key] from swizzled Vt)
#pragma unroll
    for (int ks = 0; ks < 2; ++ks) {
      bf16x8 af = *(const bf16x8*)&Ps[(wave * 16 + ln) * 72 + ks * 32 + qd * 8];
      l_acc = __builtin_amdgcn_mfma_f32_16x16x32_bf16(af, ones, l_acc, 0, 0, 0);
#pragma unroll
      for (int j = 0; j < 4; j++) {
        int d = j * 16 + ln;
        bf16x8 bv8 = *(const bf16x8*)&Vt[d * 72 + (((ks * 4 + qd) ^ (d >> 3)) << 3)];
        o_acc[j] = __builtin_amdgcn_mfma_f32_16x16x32_bf16(af, bv8, o_acc[j], 0, 0, 0);
      }
    }

    // pipelined threefry for the NEXT tile: data-independent VALU work that
    // absorbs PV lgkmcnt drain, prefetch vmcnt drain, and barrier skew.
    if (kt + 1 < kt_hi)
      gumbel_tile(base_rc + (uint32_t)((kt + 1) * 64), pf);

    __syncthreads();  // protect Ks/Vt before next staging
  }

  // epilogue: bf16 o-partials + f32 l-partials (l_acc identical across ln)
  const int pidx = ((bh << 5) | qtile) * KSPLIT + z;
  bf16_t* po = part_o + (size_t)pidx * 64 * 64;
  float* pl = part_l + (size_t)pidx * 64;

  if (ln == 0) {
#pragma unroll
    for (int r = 0; r < 4; r++) pl[wave * 16 + qd * 4 + r] = l_acc[r];
  }
#pragma unroll
  for (int j = 0; j < 4; j++)
#pragma unroll
    for (int r = 0; r < 4; r++) {
      int row = wave * 16 + qd * 4 + r;
      int col = j * 16 + ln;
      po[row * 64 + col] = (bf16_t)o_acc[j][r];
    }
}

// ---------------------------------------------------------------------------
// Combine: ab[b][qrow][h*64+d] = sum_z(o_z) / sum_z(l_z), bf16.
// One block per (bh,qtile); thread t: row = t>>2, 16 cols starting (t&3)*16.
// ---------------------------------------------------------------------------
__global__ __launch_bounds__(256, 8)
void attn_combine(const bf16_t* __restrict__ part_o,
                  const float* __restrict__ part_l, bf16_t* __restrict__ ab) {
  const int blk = blockIdx.x;      // bh*32 + qtile
  const int bh = blk >> 5, qtile = blk & 31;
  const int t = threadIdx.x;
  const int row = t >> 2, c0 = (t & 3) * 16;

  float l = 0.f;
#pragma unroll
  for (int zz = 0; zz < KSPLIT; zz++)
    l += part_l[(size_t)(blk * KSPLIT + zz) * 64 + row];
  const float linv = 1.0f / l;

  float acc[16];
#pragma unroll
  for (int i = 0; i < 16; i++) acc[i] = 0.f;
#pragma unroll
  for (int zz = 0; zz < KSPLIT; zz++) {
    const bf16_t* po =
        part_o + (size_t)(blk * KSPLIT + zz) * 64 * 64 + row * 64 + c0;
    bf16x8 a0 = *(const bf16x8*)&po[0];
    bf16x8 a1 = *(const bf16x8*)&po[8];
#pragma unroll
    for (int i = 0; i < 8; i++) { acc[i] += (float)a0[i]; acc[8 + i] += (float)a1[i]; }
  }

  const int b = bh >> 3, h = bh & 7;
  bf16_t* dst = ab + ((size_t)b * Ndim + qtile * 64 + row) * Cdim + h * 64 + c0;
  union { bf16_t h8[8]; uint4 u; } pk0, pk1;
#pragma unroll
  for (int i = 0; i < 8; i++) {
    pk0.h8[i] = (bf16_t)(acc[i] * linv);
    pk1.h8[i] = (bf16_t)(acc[8 + i] * linv);
  }
  *(uint4*)&dst[0] = pk0.u;
  *(uint4*)&dst[8] = pk1.u;
}

// ---------------------------------------------------------------------------
extern "C" void kernel_launch(void* const* d_in, const int* in_sizes, int n_in,
                              void* d_out, int out_size, void* d_ws, size_t ws_size,
                              hipStream_t stream) {
  const float* x  = (const float*)d_in[0];
  const float* y  = (const float*)d_in[1];
  const float* z  = (const float*)d_in[2];
  const float* Wq = (const float*)d_in[3];
  const float* bq = (const float*)d_in[4];
  const float* Wk = (const float*)d_in[5];
  const float* bk = (const float*)d_in[6];
  const float* Wv = (const float*)d_in[7];
  const float* bv = (const float*)d_in[8];
  const float* Wo = (const float*)d_in[9];
  const float* bo = (const float*)d_in[10];
  float* out = (float*)d_out;

  bf16_t* base = (bf16_t*)d_ws;
  const size_t NBIG = (size_t)Bdim * Ndim * Cdim;  // 4194304
  bf16_t* qb  = base;
  bf16_t* kb  = qb + NBIG;
  bf16_t* vb  = kb + NBIG;
  bf16_t* ab  = vb + NBIG;
  bf16_t* part_o = ab + NBIG;                       // 1024*KSPLIT*4096 bf16
  float* part_l = (float*)(part_o + (size_t)1024 * KSPLIT * 64 * 64);

  qkv_gemm_kernel<<<dim3(Cdim / 128, (Bdim * Ndim) / 128, 3), 256, 0, stream>>>(
      x, y, z, Wq, Wk, Wv, bq, bk, bv, qb, kb, vb);

  attn_kernel<<<dim3(Ndim / 64, Bdim * Hdim, KSPLIT), 256, 0, stream>>>(
      qb, kb, vb, part_o, part_l);

  attn_combine<<<dim3(1024), 256, 0, stream>>>(part_o, part_l, ab);

  out_gemm_kernel<<<dim3(Cdim / 64, (Bdim * Ndim) / 128), 256, 0, stream>>>(
      ab, Wo, bo, out);
}